// Round 1
// baseline (231.213 us; speedup 1.0000x reference)
//
#include <hip/hip_runtime.h>
#include <math.h>

// FBP adjoint: out[b,i0,i1,i2] = (1/A) * sum_j lerp(x[b,j,i1,:], ix(j,i0,i2))
// where ix = 16 + (i2-16)*cos(a_j) + (i0-16)*sin(a_j), and y-interp is exact
// (iy == i1 always since lin[i1] maps back to integer row index).
//
// Block = one (b, i1) pair (grid = B*33). Threads span the 1089 (i0,i2) outputs.
// x[b, :, i1, :] is staged in LDS with zero-padded rows so out-of-range corners
// read 0.0 (matches reference's w*valid masking with no per-term branches).

#define PDIM 33
#define PP   1089            // 33*33
#define AMAX 121
#define ROWW 48              // padded LDS row width (floats)
#define PADL 7               // row offset: k index -7..40 maps to 0..47
#define NV   5               // ceil(1089/256) outputs per thread

__global__ __launch_bounds__(256)
void fbp_adjoint_kernel(const float* __restrict__ x,
                        const float* __restrict__ angles,
                        float* __restrict__ out,
                        int B, int A, float invA)
{
    __shared__ float xr[AMAX * ROWW];   // padded rows: x[b, j, i1, k] at xr[j*48 + 7 + k]
    __shared__ float cs_c[AMAX];
    __shared__ float cs_s[AMAX];

    const int t   = threadIdx.x;
    const int blk = blockIdx.x;         // blk = b*33 + i1
    const int b   = blk / PDIM;
    const int i1  = blk - b * PDIM;

    // cos/sin per angle (once per block; cheap)
    for (int j = t; j < A; j += 256) {
        float a = angles[j];
        float s, c;
        sincosf(a, &s, &c);
        cs_c[j] = c;
        cs_s[j] = s;
    }

    // Stage x[b, :, i1, :] into zero-padded LDS rows.
    // Global row j: x + ((b*A + j)*33 + i1)*33, 33 contiguous floats.
    const float* xb = x + ((size_t)b * A) * PP + (size_t)i1 * PDIM;
    for (int e = t; e < A * ROWW; e += 256) {
        int j  = e / ROWW;
        int kk = e - j * ROWW;
        int k  = kk - PADL;
        float v = 0.0f;
        if (k >= 0 && k < PDIM) v = xb[(size_t)j * PP + k];
        xr[e] = v;
    }
    __syncthreads();

    // Each thread owns outputs n = t, t+256, ... (<1089): i0 = n/33, i2 = n%33.
    float accv[NV];
    float u0v[NV], u2v[NV];
    int   nidx[NV];
#pragma unroll
    for (int nn = 0; nn < NV; ++nn) {
        int n = t + nn * 256;
        bool valid = (n < PP);
        int nc = valid ? n : 0;
        int i0 = nc / PDIM;
        int i2 = nc - i0 * PDIM;
        u0v[nn] = (float)(i0 - 16);
        u2v[nn] = (float)(i2 - 16);
        nidx[nn] = valid ? n : -1;
        accv[nn] = 0.0f;
    }

    for (int j = 0; j < A; ++j) {
        float c = cs_c[j];
        float s = cs_s[j];
        const float* rowj = &xr[j * ROWW + PADL];
#pragma unroll
        for (int nn = 0; nn < NV; ++nn) {
            float ix = fmaf(u2v[nn], c, fmaf(u0v[nn], s, 16.0f));
            float fl = floorf(ix);
            int   k0 = (int)fl;
            float w1 = ix - fl;
            float w0 = 1.0f - w1;
            float v0 = rowj[k0];
            float v1 = rowj[k0 + 1];
            accv[nn] = fmaf(w0, v0, accv[nn]);
            accv[nn] = fmaf(w1, v1, accv[nn]);
        }
    }

    // Store: out[b, i0, i1, i2] = out[b*35937 + i0*1089 + i1*33 + i2]
    float* outb = out + (size_t)b * (PDIM * PP) + (size_t)i1 * PDIM;
#pragma unroll
    for (int nn = 0; nn < NV; ++nn) {
        int n = nidx[nn];
        if (n >= 0) {
            int i0 = n / PDIM;
            int i2 = n - i0 * PDIM;
            outb[(size_t)i0 * PP + i2] = accv[nn] * invA;
        }
    }
}

extern "C" void kernel_launch(void* const* d_in, const int* in_sizes, int n_in,
                              void* d_out, int out_size, void* d_ws, size_t ws_size,
                              hipStream_t stream)
{
    const float* x      = (const float*)d_in[0];
    const float* angles = (const float*)d_in[1];
    float* out          = (float*)d_out;

    const int A = in_sizes[1];                    // 121
    const int B = in_sizes[0] / (A * PP);         // 128

    dim3 grid(B * PDIM);
    dim3 block(256);
    fbp_adjoint_kernel<<<grid, block, 0, stream>>>(x, angles, out, B, A, 1.0f / (float)A);
}